// Round 8
// baseline (1291.903 us; speedup 1.0000x reference)
//
#include <hip/hip_runtime.h>
#include <math.h>

#define CCH 64
#define HH 480
#define WW 360
#define KK 32
#define HR 64
#define WR 2048
#define NPIX (HH*WW)            // 172800
#define RFNPIX (HR*WR)          // 131072
#define ZOFF 16777216u          // byte offset of zero line in rfT16
#define NEGOFF 16777344u        // byte offset of -3.4e38 sentinel line
#define GRID_S 1280             // persistent sampler grid (5 blocks/CU x 256 CU)
#define PPW 17                  // pixel-pairs per wave (1280*4*17*2 = 174080 >= 172800)
#define NPAIR 86400

typedef __attribute__((ext_vector_type(8))) short short8;
typedef __attribute__((ext_vector_type(4))) float f32x4;
typedef __attribute__((ext_vector_type(4))) int  int4_;

__device__ __forceinline__ ushort f2bf(float f) {        // RTN f32->bf16
    uint u = __float_as_uint(f);
    return (ushort)((u + 0x7fffu + ((u >> 16) & 1u)) >> 16);
}

// ---------------------------------------------------------------------------
// Weight prep: pack conv weights into MFMA A-fragment order, bf16.
// ---------------------------------------------------------------------------
__global__ __launch_bounds__(256) void k_wprep(const float* __restrict__ fw,
                                               const float* __restrict__ aw,
                                               ushort* __restrict__ wA1,
                                               ushort* __restrict__ wA2) {
    int t = blockIdx.x * 256 + threadIdx.x;
    if (t < 73728) {                                   // conv1: 4 chunks (128 ci)
        int j = t & 7, ln = (t >> 3) & 63, Mf = (t >> 9) & 3, rem = t >> 11;
        int tap = rem % 9, c = rem / 9;
        int o = Mf * 16 + (ln & 15);
        int ci = c * 32 + ((ln >> 4) & 3) * 8 + j;
        wA1[t] = f2bf(fw[(o * 128 + ci) * 9 + tap]);
    } else if (t < 73728 + 36864) {                    // conv2: 2 chunks (64 ci)
        int i = t - 73728;
        int j = i & 7, ln = (i >> 3) & 63, Mf = (i >> 9) & 3, rem = i >> 11;
        int tap = rem % 9, c = rem / 9;
        int o = Mf * 16 + (ln & 15);
        int ci = c * 32 + ((ln >> 4) & 3) * 8 + j;
        wA2[i] = f2bf(aw[(o * 64 + ci) * 9 + tap]);
    }
}

// ---------------------------------------------------------------------------
// Transpose f32 [64][npix] -> bf16 channel-last [npix][rowShorts] (cols 0..63)
// ---------------------------------------------------------------------------
__global__ __launch_bounds__(256) void k_tr(const float* __restrict__ src,
                                            ushort* __restrict__ dst,
                                            int npix, int rowShorts) {
    __shared__ float lds[64][65];
    int t = threadIdx.x;
    int pix0 = blockIdx.x * 64;
    int lx = t & 63, ty = t >> 6;
    #pragma unroll
    for (int cc = 0; cc < 64; cc += 4) {
        int c = cc + ty;
        lds[c][lx] = src[(size_t)c * npix + pix0 + lx];
    }
    __syncthreads();
    int cp = t & 31, po = t >> 5;        // cp = channel pair, po = pixel offset
    #pragma unroll
    for (int pl = po; pl < 64; pl += 8) {
        uint u = (uint)f2bf(lds[2 * cp][pl]) | ((uint)f2bf(lds[2 * cp + 1][pl]) << 16);
        *(uint*)(dst + (size_t)(pix0 + pl) * rowShorts + cp * 2) = u;
    }
}

// zero line at ZOFF, -3.4e38 line at NEGOFF, zero the 8 phase-barrier counters
__global__ void k_zero(uint* __restrict__ rft32, uint* __restrict__ bar) {
    int t = threadIdx.x;
    if (t < 32)        rft32[(ZOFF >> 2) + t] = 0;
    else if (t < 64)   rft32[(NEGOFF >> 2) + (t - 32)] = 0xFF7FFF7Fu;
    else if (t < 72)   bar[t - 64] = 0;
}

// ---------------------------------------------------------------------------
// Flow sampling v6: PERSISTENT blocks + global phase alignment.
// grid=1280 (5 blocks/CU, co-resident via __launch_bounds__(256,5); LDS
// 25.6KB/block). Each wave owns 17 pixel-pairs. 8 slice passes (slice s =
// table rows [8s,8s+8], 2.25MB, fits 4MB per-XCD L2); between passes a SOFT
// global barrier (atomic counter + bounded spin) phase-aligns all blocks so
// only ONE slice is live chip-wide at a time. Correctness does NOT depend on
// the barrier (each sample gathered in exactly its own pass); a timeout only
// costs locality. Per (pass,pair) the prep is recomputed (flow re-read is
// L3-resident), entries selected by ballot(sid==pass) and iterated via
// uniform ctz over the mask -- no sort, no dummy iterations. Running max is
// kept in LDS as packed bf16 pairs, merged once per (pass,pair).
// ---------------------------------------------------------------------------
__global__ __launch_bounds__(256, 5) void k_sample(const float* __restrict__ flow,
                                                   const char* __restrict__ rftb,
                                                   ushort* __restrict__ xin,
                                                   uint* __restrict__ bar) {
    __shared__ __align__(16) uint pbuf[4][2][32][8];   // [wave][half][k][(off,w)x4]
    __shared__ uint accL[4][PPW][2][32];               // packed bf16-pair running max
    int tid = threadIdx.x;
    int ln = tid & 63;
    int wid = tid >> 6;
    int half = ln >> 5;
    int lk = ln & 31;
    int gw = blockIdx.x * 4 + wid;
    uint laneByte = (uint)(lk * 4);
    unsigned long long hm = half ? 0xFFFFFFFF00000000ull : 0x00000000FFFFFFFFull;

    for (int j = 0; j < PPW; j++) accL[wid][j][half][lk] = 0xFF7FFF7Fu;

    #pragma unroll 1
    for (int pass = 0; pass < 8; pass++) {
        #pragma unroll 1
        for (int j = 0; j < PPW; j++) {
            int pj = gw * PPW + j;
            if (pj < NPAIR) {
                int pix = pj * 2 + half;
                const float* fp = flow + (size_t)pix * 64 + 2 * lk;
                float gy = fp[0], gx = fp[1];
                float ix = fmaf(gx, 1024.f, 1023.5f);
                float iy = fmaf(gy, 32.f, 31.5f);
                float xf = floorf(ix), yf = floorf(iy);
                float wx = ix - xf, wy = iy - yf;
                int x0 = (int)xf, y0 = (int)yf;
                bool xv0 = (unsigned)x0 < (unsigned)WR;
                bool xv1 = (unsigned)(x0 + 1) < (unsigned)WR;
                bool yv0 = (unsigned)y0 < (unsigned)HR;
                bool yv1 = (unsigned)(y0 + 1) < (unsigned)HR;
                int xc0 = x0 < 0 ? 0 : x0;
                int xc1 = x0 + 1 > WR - 1 ? WR - 1 : x0 + 1;
                int yc0 = y0 < 0 ? 0 : y0;
                int yc1 = y0 + 1 > HR - 1 ? HR - 1 : y0 + 1;
                uint o00 = (xv0 && yv0) ? (uint)(((yc0 << 11) + xc0) << 7) : ZOFF;
                uint o01 = (xv1 && yv0) ? (uint)(((yc0 << 11) + xc1) << 7) : ZOFF;
                uint o10 = (xv0 && yv1) ? (uint)(((yc1 << 11) + xc0) << 7) : ZOFF;
                uint o11 = (xv1 && yv1) ? (uint)(((yc1 << 11) + xc1) << 7) : ZOFF;
                float w00 = (1.f - wy) * (1.f - wx);
                float w01 = (1.f - wy) * wx;
                float w10 = wy * (1.f - wx);
                float w11 = wy * wx;
                *(int4_*)&pbuf[wid][half][lk][0] =
                    (int4_){(int)o00, __float_as_int(w00), (int)o01, __float_as_int(w01)};
                *(int4_*)&pbuf[wid][half][lk][4] =
                    (int4_){(int)o10, __float_as_int(w10), (int)o11, __float_as_int(w11)};

                int sid = yc0 >> 3;                          // 0..7
                unsigned long long m = __ballot(sid == pass) & hm;
                const uint* pb = &pbuf[wid][half][0][0];
                float mLo = -3.0e38f, mHi = -3.0e38f;
                while (m) {
                    int idx = (int)__builtin_ctzll(m) & 31;  // uniform per half
                    m &= m - 1;
                    const uint* e = pb + idx * 8;
                    uint2 e0 = *(const uint2*)(e + 0);       // ds_read_b64 bcast
                    uint2 e1 = *(const uint2*)(e + 2);
                    uint2 e2 = *(const uint2*)(e + 4);
                    uint2 e3 = *(const uint2*)(e + 6);
                    uint d0 = *(const uint*)(rftb + (e0.x + laneByte));
                    uint d1 = *(const uint*)(rftb + (e1.x + laneByte));
                    uint d2 = *(const uint*)(rftb + (e2.x + laneByte));
                    uint d3 = *(const uint*)(rftb + (e3.x + laneByte));
                    float W0 = __uint_as_float(e0.y);
                    float W1 = __uint_as_float(e1.y);
                    float W2 = __uint_as_float(e2.y);
                    float W3 = __uint_as_float(e3.y);
                    float vlo = W0 * __uint_as_float(d0 << 16);
                    vlo = fmaf(W1, __uint_as_float(d1 << 16), vlo);
                    vlo = fmaf(W2, __uint_as_float(d2 << 16), vlo);
                    vlo = fmaf(W3, __uint_as_float(d3 << 16), vlo);
                    float vhi = W0 * __uint_as_float(d0 & 0xffff0000u);
                    vhi = fmaf(W1, __uint_as_float(d1 & 0xffff0000u), vhi);
                    vhi = fmaf(W2, __uint_as_float(d2 & 0xffff0000u), vhi);
                    vhi = fmaf(W3, __uint_as_float(d3 & 0xffff0000u), vhi);
                    mLo = fmaxf(mLo, vlo);
                    mHi = fmaxf(mHi, vhi);
                }
                // merge pass-max into LDS packed-bf16 accumulator
                uint cur = accL[wid][j][half][lk];
                mLo = fmaxf(mLo, __uint_as_float(cur << 16));
                mHi = fmaxf(mHi, __uint_as_float(cur & 0xffff0000u));
                uint pk;
                asm("v_cvt_pk_bf16_f32 %0, %1, %2" : "=v"(pk) : "v"(mLo), "v"(mHi));
                accL[wid][j][half][lk] = pk;
            }
        }
        if (pass < 7) {                                      // soft global barrier
            __syncthreads();
            if (tid == 0) {
                atomicAdd(&bar[pass], 1u);
                int spins = 0;
                while (__hip_atomic_load(&bar[pass], __ATOMIC_RELAXED,
                                         __HIP_MEMORY_SCOPE_AGENT) < (uint)GRID_S
                       && spins < 150000) {
                    __builtin_amdgcn_s_sleep(2);
                    spins++;
                }
            }
            __syncthreads();
        }
    }

    #pragma unroll 1
    for (int j = 0; j < PPW; j++) {
        int pj = gw * PPW + j;
        if (pj < NPAIR) {
            int pix = pj * 2 + half;
            uint v = accL[wid][j][half][lk];
            __builtin_nontemporal_store(
                v, (uint*)((char*)xin + (size_t)pix * 256 + 128 + lk * 4));
        }
    }
}

// ---------------------------------------------------------------------------
// conv1: implicit-GEMM MFMA, M=64(o), N=192 (180-px half-row + pad), K=1152.
// Input xin bf16 [p][128]. Output res_t f32 [p][64] (BN+ReLU applied).
// ---------------------------------------------------------------------------
__global__ __launch_bounds__(256) void k_mconv1(const ushort* __restrict__ xin,
                                                const ushort* __restrict__ wA,
                                                const float* __restrict__ g,
                                                const float* __restrict__ b,
                                                const float* __restrict__ mn,
                                                const float* __restrict__ vr,
                                                float* __restrict__ res_t) {
    __shared__ __align__(16) ushort xt[3][194][32];
    int tid = threadIdx.x;
    int h = blockIdx.x >> 1, w0 = (blockIdx.x & 1) * 180;
    int wid = tid >> 6, ln = tid & 63;
    f32x4 acc[4][3];
    #pragma unroll
    for (int m = 0; m < 4; m++)
        #pragma unroll
        for (int nf = 0; nf < 3; nf++) acc[m][nf] = (f32x4){0.f, 0.f, 0.f, 0.f};

    for (int c = 0; c < 4; c++) {
        __syncthreads();
        for (int i = tid; i < 2184; i += 256) {          // 546 slots x 4 quads
            int q = i & 3, s = i >> 2;
            int r = s / 182, pw = s - r * 182;
            int gh = h + r - 1;
            int gw = w0 + pw - 1;
            if (gw < 0) gw += WW;
            if (gw >= WW) gw -= WW;
            int4_ val = {0, 0, 0, 0};
            if ((unsigned)gh < (unsigned)HH)
                val = *(const int4_*)(xin + ((size_t)(gh * WW + gw) * 128 + c * 32 + q * 8));
            *(int4_*)&xt[r][pw][(q ^ (pw & 3)) * 8] = val;
        }
        __syncthreads();
        #pragma unroll
        for (int tap = 0; tap < 9; tap++) {
            int dh = tap / 3, dw = tap % 3;
            short8 aF[4];
            #pragma unroll
            for (int m = 0; m < 4; m++)
                aF[m] = *(const short8*)(wA + (size_t)(((c * 9 + tap) * 4 + m) * 64 + ln) * 8);
            short8 bF[3];
            #pragma unroll
            for (int nf = 0; nf < 3; nf++) {
                int pw = wid * 48 + nf * 16 + (ln & 15) + dw;
                bF[nf] = *(const short8*)&xt[dh][pw][((((ln >> 4) & 3)) ^ (pw & 3)) * 8];
            }
            #pragma unroll
            for (int m = 0; m < 4; m++)
                #pragma unroll
                for (int nf = 0; nf < 3; nf++)
                    acc[m][nf] = __builtin_amdgcn_mfma_f32_16x16x32_bf16(aF[m], bF[nf], acc[m][nf], 0, 0, 0);
        }
    }
    // epilogue: BN + ReLU -> res_t[p][o]
    #pragma unroll
    for (int m = 0; m < 4; m++) {
        #pragma unroll
        for (int reg = 0; reg < 4; reg++) {
            int o = m * 16 + ((ln >> 4) & 3) * 4 + reg;
            float sc = g[o] * rsqrtf(vr[o] + 1e-5f);
            float bi = b[o] - mn[o] * sc;
            #pragma unroll
            for (int nf = 0; nf < 3; nf++) {
                int n = wid * 48 + nf * 16 + (ln & 15);
                if (n < 180) {
                    int P = h * WW + w0 + n;
                    float v = fmaf(acc[m][nf][reg], sc, bi);
                    res_t[(size_t)P * 64 + o] = fmaxf(v, 0.f);
                }
            }
        }
    }
}

// ---------------------------------------------------------------------------
// conv2: same GEMM (K=576) on res_t (f32 -> bf16 staged), BN + channel
// softmax + final out = polar + res*att.
// ---------------------------------------------------------------------------
__global__ __launch_bounds__(256) void k_mconv2(const float* __restrict__ res_t,
                                                const float* __restrict__ polar,
                                                const ushort* __restrict__ wA,
                                                const float* __restrict__ g,
                                                const float* __restrict__ b,
                                                const float* __restrict__ mn,
                                                const float* __restrict__ vr,
                                                float* __restrict__ out) {
    __shared__ __align__(16) ushort xt[3][194][32];
    int tid = threadIdx.x;
    int h = blockIdx.x >> 1, w0 = (blockIdx.x & 1) * 180;
    int wid = tid >> 6, ln = tid & 63;
    f32x4 acc[4][3];
    #pragma unroll
    for (int m = 0; m < 4; m++)
        #pragma unroll
        for (int nf = 0; nf < 3; nf++) acc[m][nf] = (f32x4){0.f, 0.f, 0.f, 0.f};

    for (int c = 0; c < 2; c++) {
        __syncthreads();
        for (int i = tid; i < 2184; i += 256) {
            int q = i & 3, s = i >> 2;
            int r = s / 182, pw = s - r * 182;
            int gh = h + r - 1;
            int gw = w0 + pw - 1;
            if (gw < 0) gw += WW;
            if (gw >= WW) gw -= WW;
            int4_ val = {0, 0, 0, 0};
            if ((unsigned)gh < (unsigned)HH) {
                const float* src = res_t + ((size_t)(gh * WW + gw) * 64 + c * 32 + q * 8);
                f32x4 va = *(const f32x4*)src;
                f32x4 vb = *(const f32x4*)(src + 4);
                uint u0, u1, u2, u3;
                asm("v_cvt_pk_bf16_f32 %0, %1, %2" : "=v"(u0) : "v"(va[0]), "v"(va[1]));
                asm("v_cvt_pk_bf16_f32 %0, %1, %2" : "=v"(u1) : "v"(va[2]), "v"(va[3]));
                asm("v_cvt_pk_bf16_f32 %0, %1, %2" : "=v"(u2) : "v"(vb[0]), "v"(vb[1]));
                asm("v_cvt_pk_bf16_f32 %0, %1, %2" : "=v"(u3) : "v"(vb[2]), "v"(vb[3]));
                val = (int4_){(int)u0, (int)u1, (int)u2, (int)u3};
            }
            *(int4_*)&xt[r][pw][(q ^ (pw & 3)) * 8] = val;
        }
        __syncthreads();
        #pragma unroll
        for (int tap = 0; tap < 9; tap++) {
            int dh = tap / 3, dw = tap % 3;
            short8 aF[4];
            #pragma unroll
            for (int m = 0; m < 4; m++)
                aF[m] = *(const short8*)(wA + (size_t)(((c * 9 + tap) * 4 + m) * 64 + ln) * 8);
            short8 bF[3];
            #pragma unroll
            for (int nf = 0; nf < 3; nf++) {
                int pw = wid * 48 + nf * 16 + (ln & 15) + dw;
                bF[nf] = *(const short8*)&xt[dh][pw][((((ln >> 4) & 3)) ^ (pw & 3)) * 8];
            }
            #pragma unroll
            for (int m = 0; m < 4; m++)
                #pragma unroll
                for (int nf = 0; nf < 3; nf++)
                    acc[m][nf] = __builtin_amdgcn_mfma_f32_16x16x32_bf16(aF[m], bF[nf], acc[m][nf], 0, 0, 0);
        }
    }
    // epilogue: BN -> softmax over 64 channels -> out = polar + res*att
    #pragma unroll
    for (int m = 0; m < 4; m++) {
        #pragma unroll
        for (int reg = 0; reg < 4; reg++) {
            int o = m * 16 + ((ln >> 4) & 3) * 4 + reg;
            float sc = g[o] * rsqrtf(vr[o] + 1e-5f);
            float bi = b[o] - mn[o] * sc;
            #pragma unroll
            for (int nf = 0; nf < 3; nf++)
                acc[m][nf][reg] = fmaf(acc[m][nf][reg], sc, bi);
        }
    }
    #pragma unroll
    for (int nf = 0; nf < 3; nf++) {
        float mx = -3.0e38f;
        #pragma unroll
        for (int m = 0; m < 4; m++)
            #pragma unroll
            for (int reg = 0; reg < 4; reg++) mx = fmaxf(mx, acc[m][nf][reg]);
        mx = fmaxf(mx, __shfl_xor(mx, 16));
        mx = fmaxf(mx, __shfl_xor(mx, 32));
        float s = 0.f;
        #pragma unroll
        for (int m = 0; m < 4; m++)
            #pragma unroll
            for (int reg = 0; reg < 4; reg++) {
                float e = __expf(acc[m][nf][reg] - mx);
                acc[m][nf][reg] = e;
                s += e;
            }
        s += __shfl_xor(s, 16);
        s += __shfl_xor(s, 32);
        float rinv = 1.f / s;
        int n = wid * 48 + nf * 16 + (ln & 15);
        if (n < 180) {
            int P = h * WW + w0 + n;
            #pragma unroll
            for (int m = 0; m < 4; m++)
                #pragma unroll
                for (int reg = 0; reg < 4; reg++) {
                    int o = m * 16 + ((ln >> 4) & 3) * 4 + reg;
                    float att = acc[m][nf][reg] * rinv;
                    out[(size_t)o * NPIX + P] =
                        fmaf(res_t[(size_t)P * 64 + o], att, polar[(size_t)o * NPIX + P]);
                }
        }
    }
}

// ---------------------------------------------------------------------------
extern "C" void kernel_launch(void* const* d_in, const int* in_sizes, int n_in,
                              void* d_out, int out_size, void* d_ws, size_t ws_size,
                              hipStream_t stream) {
    const float* flow  = (const float*)d_in[0];
    const float* polar = (const float*)d_in[1];
    const float* rf    = (const float*)d_in[2];
    const float* fw    = (const float*)d_in[3];
    const float* fg    = (const float*)d_in[4];
    const float* fb    = (const float*)d_in[5];
    const float* fm    = (const float*)d_in[6];
    const float* fv    = (const float*)d_in[7];
    const float* aw    = (const float*)d_in[8];
    const float* ag    = (const float*)d_in[9];
    const float* ab    = (const float*)d_in[10];
    const float* am    = (const float*)d_in[11];
    const float* av    = (const float*)d_in[12];
    float* out = (float*)d_out;

    char* wsb = (char*)d_ws;
    ushort* xin   = (ushort*)wsb;                         // [NPIX][128] bf16 = 44,236,800 B
    ushort* rft   = (ushort*)(wsb + 44236800);            // [RFNPIX][64] bf16 + sentinel lines
    float*  res_t = (float*)(wsb + 61014272);             // [NPIX][64] f32 = 44,236,800 B
    ushort* wA1   = (ushort*)(wsb + 105251072);           // 147,456 B
    ushort* wA2   = wA1 + 73728;                          // 73,728 B
    uint*   bar   = (uint*)(wsb + 105472256);             // 8 phase counters

    k_wprep<<<432, 256, 0, stream>>>(fw, aw, wA1, wA2);
    k_tr<<<NPIX / 64, 256, 0, stream>>>(polar, xin, NPIX, 128);
    k_tr<<<RFNPIX / 64, 256, 0, stream>>>(rf, rft, RFNPIX, 64);
    k_zero<<<1, 128, 0, stream>>>((uint*)rft, bar);
    k_sample<<<GRID_S, 256, 0, stream>>>(flow, (const char*)rft, xin, bar);
    k_mconv1<<<960, 256, 0, stream>>>(xin, wA1, fg, fb, fm, fv, res_t);
    k_mconv2<<<960, 256, 0, stream>>>(res_t, polar, wA2, ag, ab, am, av, out);
}